// Round 1
// baseline (54.867 us; speedup 1.0000x reference)
//
#include <hip/hip_runtime.h>
#include <math.h>

#define Hh 64
#define Ww 64
#define Nn 512
#define Bb 32

// Kernel 1: per-(b,n) gaussian parameter precompute.
// Output params[b][n][8] = { px, py, a2, b2, c2, ocr, ocg, ocb }
// where sigma-exponent is expressed as exp2( a2*dx^2 + b2*dx*dy + c2*dy^2 )
// (i.e. -log2(e) * (0.5*con_a dx^2 + con_b dx dy + 0.5*con_c dy^2)),
// and oc = opacity * color.
__global__ __launch_bounds__(256) void gs_prep(const float* __restrict__ data,
                                               const float* __restrict__ opacity,
                                               float* __restrict__ params) {
    int i = blockIdx.x * 256 + threadIdx.x;   // i in [0, B*N)
    if (i >= Bb * Nn) return;
    int n = i & (Nn - 1);

    const float4* dp = (const float4*)(data) + (size_t)i * 2;
    float4 d0 = dp[0];   // data[...,0..3]
    float4 d1 = dp[1];   // data[...,4..7]

    float xy0 = tanhf(d0.x);
    float xy1 = tanhf(d0.y);
    float s0 = fabsf(d0.z) + 0.3f;
    float s1 = fabsf(d0.w) + 0.3f;
    float theta = (1.0f / (1.0f + expf(-d1.x))) * (2.0f * (float)M_PI);
    float c = cosf(theta);
    float s = sinf(theta);

    float px = 0.5f * ((xy0 + 1.0f) * (float)Ww - 1.0f);
    float py = 0.5f * ((xy1 + 1.0f) * (float)Hh - 1.0f);

    float s0sq = s0 * s0, s1sq = s1 * s1;
    float cov_a = c * c * s0sq + s * s * s1sq;
    float cov_b = c * s * (s0sq - s1sq);
    float cov_c = s * s * s0sq + c * c * s1sq;
    float det = cov_a * cov_c - cov_b * cov_b;
    float inv = 1.0f / det;
    float con_a = cov_c * inv;
    float con_b = -cov_b * inv;
    float con_c = cov_a * inv;

    const float L2E = 1.4426950408889634f;   // log2(e)
    float a2 = -0.5f * con_a * L2E;
    float b2 = -con_b * L2E;
    float c2 = -0.5f * con_c * L2E;

    float op = opacity[n];

    float4 o0 = make_float4(px, py, a2, b2);
    float4 o1 = make_float4(c2, op * d1.y, op * d1.z, op * d1.w);
    float4* outp = (float4*)(params) + (size_t)i * 2;
    outp[0] = o0;
    outp[1] = o1;
}

// Kernel 2: one thread per pixel; loop over all 512 gaussians of this batch.
// Param reads are block-uniform (b derived from blockIdx only) -> scalar loads.
__global__ __launch_bounds__(256) void gs_render(const float* __restrict__ params,
                                                 float* __restrict__ out) {
    int b   = blockIdx.x >> 4;                         // 16 blocks per batch
    int pix = ((blockIdx.x & 15) << 8) | threadIdx.x;  // 0..4095
    float fx = (float)(pix & 63);
    float fy = (float)(pix >> 6);

    const float4* pp = (const float4*)(params + (size_t)b * (Nn * 8));

    float accr = 0.0f, accg = 0.0f, accb = 0.0f;
#pragma unroll 4
    for (int n = 0; n < Nn; ++n) {
        float4 A  = pp[2 * n];       // px, py, a2, b2
        float4 Bv = pp[2 * n + 1];   // c2, ocr, ocg, ocb
        float dx  = fx - A.x;
        float dy  = fy - A.y;
        float bdy = A.w * dy;
        float u   = fmaf(A.z, dx, bdy);        // a2*dx + b2*dy
        float t   = (Bv.x * dy) * dy;          // c2*dy^2
        float sg  = fmaf(u, dx, t);            // a2*dx^2 + b2*dx*dy + c2*dy^2
        float e   = __builtin_amdgcn_exp2f(sg);
        accr = fmaf(e, Bv.y, accr);
        accg = fmaf(e, Bv.z, accg);
        accb = fmaf(e, Bv.w, accb);
    }

    size_t base = (size_t)b * 3 * 4096 + (size_t)pix;
    out[base]        = accr;
    out[base + 4096] = accg;
    out[base + 8192] = accb;
}

extern "C" void kernel_launch(void* const* d_in, const int* in_sizes, int n_in,
                              void* d_out, int out_size, void* d_ws, size_t ws_size,
                              hipStream_t stream) {
    const float* data    = (const float*)d_in[0];
    const float* opacity = (const float*)d_in[1];
    float* params = (float*)d_ws;   // needs B*N*8*4 = 512 KB
    float* out    = (float*)d_out;

    gs_prep<<<(Bb * Nn + 255) / 256, 256, 0, stream>>>(data, opacity, params);
    gs_render<<<(Bb * Hh * Ww) / 256, 256, 0, stream>>>(params, out);
}

// Round 2
// 36.610 us; speedup vs baseline: 1.4987x; 1.4987x over previous
//
#include <hip/hip_runtime.h>
#include <math.h>

#define Hh 64
#define Ww 64
#define Nn 512
#define Bb 32
#define NCHUNK 4
#define CHUNK (Nn / NCHUNK)   // 128

// Kernel 1: per-(b,n) gaussian parameter precompute.
// params[b][n][8] = { px, py, a2, b2, c2, ocr, ocg, ocb }
// exponent form: exp2( a2*dx^2 + b2*dx*dy + c2*dy^2 ), oc = opacity*color.
__global__ __launch_bounds__(256) void gs_prep(const float* __restrict__ data,
                                               const float* __restrict__ opacity,
                                               float* __restrict__ params) {
    int i = blockIdx.x * 256 + threadIdx.x;   // i in [0, B*N)
    if (i >= Bb * Nn) return;
    int n = i & (Nn - 1);

    const float4* dp = (const float4*)(data) + (size_t)i * 2;
    float4 d0 = dp[0];   // data[...,0..3]
    float4 d1 = dp[1];   // data[...,4..7]

    float xy0 = tanhf(d0.x);
    float xy1 = tanhf(d0.y);
    float s0 = fabsf(d0.z) + 0.3f;
    float s1 = fabsf(d0.w) + 0.3f;
    float theta = (1.0f / (1.0f + expf(-d1.x))) * (2.0f * (float)M_PI);
    float c = cosf(theta);
    float s = sinf(theta);

    float px = 0.5f * ((xy0 + 1.0f) * (float)Ww - 1.0f);
    float py = 0.5f * ((xy1 + 1.0f) * (float)Hh - 1.0f);

    float s0sq = s0 * s0, s1sq = s1 * s1;
    float cov_a = c * c * s0sq + s * s * s1sq;
    float cov_b = c * s * (s0sq - s1sq);
    float cov_c = s * s * s0sq + c * c * s1sq;
    float det = cov_a * cov_c - cov_b * cov_b;
    float inv = 1.0f / det;
    float con_a = cov_c * inv;
    float con_b = -cov_b * inv;
    float con_c = cov_a * inv;

    const float L2E = 1.4426950408889634f;   // log2(e)
    float a2 = -0.5f * con_a * L2E;
    float b2 = -con_b * L2E;
    float c2 = -0.5f * con_c * L2E;

    float op = opacity[n];

    float4 o0 = make_float4(px, py, a2, b2);
    float4 o1 = make_float4(c2, op * d1.y, op * d1.z, op * d1.w);
    float4* outp = (float4*)(params) + (size_t)i * 2;
    outp[0] = o0;
    outp[1] = o1;
}

// Kernel 2: one thread per pixel, one block per (batch, pixel-group, N-chunk).
// 2048 blocks -> 8 waves/SIMD. Param reads are block-uniform -> scalar loads.
// Chunks accumulate into d_out via atomicAdd (d_out pre-zeroed on stream).
__global__ __launch_bounds__(256) void gs_render(const float* __restrict__ params,
                                                 float* __restrict__ out) {
    int chunk = blockIdx.x & (NCHUNK - 1);
    int grp   = (blockIdx.x >> 2) & 15;
    int b     = blockIdx.x >> 6;
    int pix   = (grp << 8) | threadIdx.x;              // 0..4095
    float fx = (float)(pix & 63);
    float fy = (float)(pix >> 6);

    const float4* pp = (const float4*)(params + (size_t)b * (Nn * 8)) +
                       (size_t)chunk * CHUNK * 2;

    float accr = 0.0f, accg = 0.0f, accb = 0.0f;
#pragma unroll 4
    for (int n = 0; n < CHUNK; ++n) {
        float4 A  = pp[2 * n];       // px, py, a2, b2
        float4 Bv = pp[2 * n + 1];   // c2, ocr, ocg, ocb
        float dx  = fx - A.x;
        float dy  = fy - A.y;
        float bdy = A.w * dy;
        float u   = fmaf(A.z, dx, bdy);        // a2*dx + b2*dy
        float t   = (Bv.x * dy) * dy;          // c2*dy^2
        float sg  = fmaf(u, dx, t);            // a2*dx^2 + b2*dx*dy + c2*dy^2
        float e   = __builtin_amdgcn_exp2f(sg);
        accr = fmaf(e, Bv.y, accr);
        accg = fmaf(e, Bv.z, accg);
        accb = fmaf(e, Bv.w, accb);
    }

    size_t base = (size_t)b * 3 * 4096 + (size_t)pix;
    atomicAdd(&out[base],        accr);
    atomicAdd(&out[base + 4096], accg);
    atomicAdd(&out[base + 8192], accb);
}

extern "C" void kernel_launch(void* const* d_in, const int* in_sizes, int n_in,
                              void* d_out, int out_size, void* d_ws, size_t ws_size,
                              hipStream_t stream) {
    const float* data    = (const float*)d_in[0];
    const float* opacity = (const float*)d_in[1];
    float* params = (float*)d_ws;   // needs B*N*8*4 = 512 KB
    float* out    = (float*)d_out;

    hipMemsetAsync(d_out, 0, (size_t)out_size * sizeof(float), stream);
    gs_prep<<<(Bb * Nn + 255) / 256, 256, 0, stream>>>(data, opacity, params);
    gs_render<<<Bb * 16 * NCHUNK, 256, 0, stream>>>(params, out);
}